// Round 17
// baseline (314.710 us; speedup 1.0000x reference)
//
#include <hip/hip_runtime.h>
#include <cstdint>

#define BB 4
#define CC 48
#define HW 16384
#define D1 384
#define HEADS 8

typedef unsigned short ushort_t;
typedef __attribute__((ext_vector_type(8))) short short8;
typedef __attribute__((ext_vector_type(4))) float f32x4;
typedef __attribute__((ext_vector_type(16))) float f32x16;

__device__ __forceinline__ float bf2f(ushort_t u){
  union{uint32_t i; float f;} v; v.i = ((uint32_t)u)<<16; return v.f;
}
__device__ __forceinline__ ushort_t f2bf(float f){
  union{float f; uint32_t i;} v; v.f=f;
  uint32_t x = v.i;
  uint32_t r = (x + 0x7fff + ((x>>16)&1)) >> 16;
  return (ushort_t)r;
}

// fused-weight precompute, FRAGMENT-MAJOR for 32x32x16 B-operand:
// element (oc, kk): slice=oc>>7, nt=(oc&127)>>5, l31=oc&31; chunk=kk>>4, lhalf=(kk&15)>>3, j=kk&7.
// addr = ((slice*28 + chunk)*4 + nt)*512 + (lhalf*32+l31)*8 + j.
// Also zeroes qn2(3072)+xst(1728) = 4800 floats (contiguous).
__global__ __launch_bounds__(256) void k_wf(const float* __restrict__ dw,
                                            const float* __restrict__ qw,
                                            ushort_t* __restrict__ wfp,
                                            float* __restrict__ qn2){
  int oc = blockIdx.x, tid = threadIdx.x;
  if(oc < 19){ int i = oc*256 + tid; if(i < 4800) qn2[i] = 0.f; }
  int slice = oc>>7, ocl = oc&127;
  int nt = ocl>>5, l31 = ocl&31;
  for(int kk=tid; kk<448; kk+=256){
    int t = kk/48, c = kk - t*48;
    float s = 0.f;
    if(t < 9){
      #pragma unroll
      for(int j=0;j<8;j++)
        s += dw[(size_t)oc*72 + j*9 + t] * qw[(size_t)((oc>>3)*8 + j)*48 + c];
    }
    int chunk = kk>>4, kr = kk&15, lhalf = kr>>3, j = kr&7;
    size_t addr = (((size_t)(slice*28 + chunk)*4 + nt)*512) + (size_t)(lhalf*32 + l31)*8 + j;
    wfp[addr] = f2bf(s);
  }
}

// x -> channel-last bf16 with 1-px zero border, FUSED with boundary-stats accumulation.
__global__ __launch_bounds__(256) void k_xpose(const float* __restrict__ x,
                                               ushort_t* __restrict__ xb16,
                                               float* __restrict__ xst){
  int gy = blockIdx.x;      // 0..129
  int b  = blockIdx.y;
  ushort_t* orow = xb16 + ((size_t)b*130 + gy)*130*48;
  int tid = threadIdx.x;
  if(gy==0 || gy==129){
    short8 z = {0,0,0,0,0,0,0,0};
    for(int u=tid; u<780; u+=256) *(short8*)(orow + u*8) = z;
    return;
  }
  __shared__ float xl[48*128];
  const float* xr = x + (size_t)b*CC*HW + (size_t)(gy-1)*128;
  for(int i=tid;i<6144;i+=256){
    int c=i>>7, p=i&127;
    xl[c*128+p] = xr[(size_t)c*HW + p];
  }
  __syncthreads();
  for(int u=tid; u<780; u+=256){
    int gx = u/6, s = u-gx*6;
    ushort_t tmp[8];
    if(gx==0||gx==129){
      #pragma unroll
      for(int j=0;j<8;j++) tmp[j]=0;
    } else {
      #pragma unroll
      for(int j=0;j<8;j++) tmp[j] = f2bf(xl[(s*8+j)*128 + (gx-1)]);
    }
    *(short8*)(orow + (size_t)u*8) = *(short8*)tmp;
  }
  if(tid < 48){
    const float* row = &xl[tid*128];
    float a0=0,a1=0,a2=0,a3=0;
    #pragma unroll 8
    for(int p=0;p<128;p+=4){ a0+=row[p]; a1+=row[p+1]; a2+=row[p+2]; a3+=row[p+3]; }
    float s = (a0+a1)+(a2+a3);
    float* o = xst + ((size_t)b*48 + tid)*9;
    atomicAdd(&o[0], s);
    atomicAdd(&o[3], row[0]);
    atomicAdd(&o[4], row[127]);
    if(gy==1)  { o[1]=s; o[5]=row[0]; o[6]=row[127]; }
    if(gy==128){ o[2]=s; o[7]=row[0]; o[8]=row[127]; }
  }
}

// dense 3x3 conv 48->1152 as MFMA GEMM using 32x32x16: wave = 32 pos x 128 oc.
// LDS B-traffic halves vs 16x16x32 (128 FLOP/LDS-byte); per-chunk addr consts
// fold at compile time (chunks of K=16 never cross a 3x3-tap boundary).
#define HROWC 64
__global__ __launch_bounds__(256,3) void k_conv(const ushort_t* __restrict__ xb16,
                                                const ushort_t* __restrict__ wfp,
                                                ushort_t* __restrict__ qkvd){
  __shared__ __align__(16) ushort_t xs[180*HROWC];   // 23040 B
  int tid  = threadIdx.x;
  int wave = tid>>6, lane = tid&63;
  int l31 = lane&31, lhalf = lane>>5;
  int tile = blockIdx.x;              // 128 tiles: 16 (y) x 8 (x)
  int ty0 = (tile>>3)*8, tx0 = (tile&7)*16;
  int slice = blockIdx.y;
  int b   = blockIdx.z;

  // ---- staging: 8 independent loads in flight, then predicated LDS writes ----
  {
    const ushort_t* xh = xb16 + ((size_t)b*16900 + (size_t)ty0*130 + tx0)*48;
    short8 vbuf[8];
    #pragma unroll
    for(int i=0;i<8;i++){
      int u = tid + i*256;
      int uu = (u < 1944) ? u : 1943;
      int r = uu/6, g = uu - r*6;
      int hy = r/18, hx = r - hy*18;
      vbuf[i] = *(const short8*)(xh + ((size_t)hy*130 + hx)*48 + g*8);
    }
    #pragma unroll
    for(int i=0;i<8;i++){
      int u = tid + i*256;
      if(u < 1944){
        int r = u/6, g = u - r*6;
        *(short8*)(xs + r*HROWC + ((g ^ (r&7))<<3)) = vbuf[i];
      }
    }
  }
  __syncthreads();

  // per-lane A (halo) position: p = wave*32 + l31
  int p  = wave*32 + l31;
  int py = p>>4, px = p&15;
  int rb = (py+1)*18 + px + 1;

  const ushort_t* BbF = wfp + (size_t)slice*(28*4*512) + (size_t)lane*8;
  f32x16 Cacc[4];
  #pragma unroll
  for(int nt=0;nt<4;nt++)
    #pragma unroll
    for(int e=0;e<16;e++) Cacc[nt][e] = 0.f;

  short8 Bc[4], Bn[4];
  #pragma unroll
  for(int nt=0;nt<4;nt++) Bc[nt] = *(const short8*)(BbF + (size_t)nt*512);

  #pragma unroll
  for(int chunk=0; chunk<28; chunk++){
    if(chunk < 27){
      #pragma unroll
      for(int nt=0;nt<4;nt++)
        Bn[nt] = *(const short8*)(BbF + (size_t)((chunk+1)*4 + nt)*512);
    }
    int t  = chunk/3;                 // compile-time per unrolled chunk
    int tc = (t<9) ? t : 8;           // weights zero for t=9; halo junk harmless
    int dy = tc/3, dx = tc - dy*3;
    int drow = (dy-1)*18 + (dx-1);
    int g = (chunk - t*3)*2 + lhalf;  // (chunk%3)*2 + lhalf
    int r = rb + drow;
    short8 Af = *(const short8*)(xs + r*HROWC + ((g ^ (r&7))<<3));
    #pragma unroll
    for(int nt=0;nt<4;nt++)
      Cacc[nt] = __builtin_amdgcn_mfma_f32_32x32x16_bf16(Af, Bc[nt], Cacc[nt], 0,0,0);
    #pragma unroll
    for(int nt=0;nt<4;nt++) Bc[nt] = Bn[nt];
  }

  // ---- epilogue: C col=lane&31 (oc), row=(reg&3)+8*(reg>>2)+4*lhalf (pos) ----
  #pragma unroll
  for(int nt=0;nt<4;nt++){
    int oc = slice*128 + nt*32 + l31;
    ushort_t* orow = qkvd + ((size_t)b*1152 + oc)*HW;
    #pragma unroll
    for(int grp=0; grp<4; grp++){
      int row = lhalf*4 + grp*8;
      int pp  = wave*32 + row;
      int gpos = (ty0 + (pp>>4))*128 + tx0 + (pp&15);
      ushort_t pk[4];
      #pragma unroll
      for(int rr=0;rr<4;rr++) pk[rr] = f2bf(Cacc[nt][grp*4+rr]);
      *(uint2*)(orow + gpos) = *(uint2*)pk;
    }
  }
}

// S = Q K^T per (b,h) via MFMA; norms free as diag(Q Q^T), diag(K K^T).
__global__ __launch_bounds__(256,3) void k_S(const ushort_t* __restrict__ qkvd,
                                             float* __restrict__ Spart,
                                             float* __restrict__ qn2){
  __shared__ __align__(16) ushort_t qk[96*264];   // 50688 B
  int tid = threadIdx.x;
  int blk = blockIdx.x, h = blockIdx.y, b = blockIdx.z;
  int wave = tid>>6, lane = tid&63;
  int quad = lane>>4, mrow = lane&15;
  const ushort_t* qb = qkvd + ((size_t)b*1152 + h*48)*HW;
  const ushort_t* kb = qb + (size_t)384*HW;

  f32x4 accS[3][3], accq[3], acck[3];
  #pragma unroll
  for(int mt=0;mt<3;mt++){
    accq[mt] = (f32x4){0.f,0.f,0.f,0.f};
    acck[mt] = (f32x4){0.f,0.f,0.f,0.f};
    #pragma unroll
    for(int nt=0;nt<3;nt++) accS[mt][nt] = (f32x4){0.f,0.f,0.f,0.f};
  }

  for(int half=0; half<2; half++){
    int p0 = blk*512 + half*256;
    __syncthreads();
    for(int u=tid; u<3072; u+=256){            // 96 ch x 32 b128-units
      int ch = u>>5, px = u&31;
      const ushort_t* src = ((ch<48) ? qb + (size_t)ch*HW
                                     : kb + (size_t)(ch-48)*HW) + p0 + px*8;
      *(short8*)(qk + ch*264 + px*8) = *(const short8*)src;
    }
    __syncthreads();
    #pragma unroll
    for(int ks=0; ks<2; ks++){
      int koff = wave*64 + ks*32 + quad*8;
      short8 Aq[3], Bk[3];
      #pragma unroll
      for(int mt=0;mt<3;mt++) Aq[mt] = *(const short8*)(qk + (mt*16+mrow)*264 + koff);
      #pragma unroll
      for(int nt=0;nt<3;nt++) Bk[nt] = *(const short8*)(qk + (48+nt*16+mrow)*264 + koff);
      #pragma unroll
      for(int mt=0;mt<3;mt++){
        accq[mt] = __builtin_amdgcn_mfma_f32_16x16x32_bf16(Aq[mt], Aq[mt], accq[mt], 0,0,0);
        acck[mt] = __builtin_amdgcn_mfma_f32_16x16x32_bf16(Bk[mt], Bk[mt], acck[mt], 0,0,0);
        #pragma unroll
        for(int nt=0;nt<3;nt++)
          accS[mt][nt] = __builtin_amdgcn_mfma_f32_16x16x32_bf16(Aq[mt], Bk[nt], accS[mt][nt], 0,0,0);
      }
    }
  }
  __syncthreads();
  float* scr = (float*)qk;
  #pragma unroll
  for(int mt=0;mt<3;mt++)
    #pragma unroll
    for(int nt=0;nt<3;nt++)
      #pragma unroll
      for(int r=0;r<4;r++)
        scr[wave*2304 + (mt*16+quad*4+r)*48 + nt*16 + mrow] = accS[mt][nt][r];
  __syncthreads();
  float* outp = Spart + ((size_t)((b*HEADS+h)*32 + blk))*2304;
  for(int idx=tid; idx<2304; idx+=256)
    outp[idx] = scr[idx] + scr[2304+idx] + scr[4608+idx] + scr[6912+idx];
  int rr = mrow - (quad<<2);
  #pragma unroll
  for(int r=0;r<4;r++){
    if(rr == r){
      #pragma unroll
      for(int mt=0;mt<3;mt++){
        atomicAdd(qn2 + (size_t)b*D1 + h*48 + mt*16 + mrow, accq[mt][r]);
        atomicAdd(qn2 + 1536 + (size_t)b*D1 + h*48 + mt*16 + mrow, acck[mt][r]);
      }
    }
  }
}

// per b: l-stats from x-stats -> mean -> fc1 -> relu -> fc2 -> swish -> constv = po1@L
__global__ __launch_bounds__(384) void k_mlp(const float* __restrict__ xst,
                                             const float* __restrict__ qw,
                                             const float* __restrict__ dw,
                                             const float* __restrict__ fc1w,
                                             const float* __restrict__ fc1b,
                                             const float* __restrict__ fc2w,
                                             const float* __restrict__ fc2b,
                                             const float* __restrict__ po1,
                                             float* __restrict__ constv){
  int b = blockIdx.x, tid = threadIdx.x;
  __shared__ float xsl[432];
  __shared__ float lst[3456];
  __shared__ float avg[384];
  __shared__ float y1[24];
  __shared__ float Lb[384];
  for(int i=tid;i<432;i+=384) xsl[i] = xst[(size_t)b*432 + i];
  __syncthreads();
  {
    float st[9];
    #pragma unroll
    for(int s=0;s<9;s++) st[s]=0.f;
    const float* w = qw + (size_t)(1152+tid)*48;
    for(int c=0;c<48;c++){
      float wv = w[c];
      #pragma unroll
      for(int s=0;s<9;s++) st[s] += wv*xsl[c*9+s];
    }
    #pragma unroll
    for(int s=0;s<9;s++) lst[tid*9+s] = st[s];
  }
  __syncthreads();
  {
    int base = tid & ~7;
    const float* ls = &lst[base*9];
    float s = 0.f;
    #pragma unroll
    for(int i=0;i<8;i++){
      float T=ls[i*9+0],R0=ls[i*9+1],R1=ls[i*9+2],C0=ls[i*9+3],C1=ls[i*9+4];
      float c00=ls[i*9+5],c0W=ls[i*9+6],cH0=ls[i*9+7],cHW=ls[i*9+8];
      const float* wp = dw + (size_t)(1152+tid)*72 + i*9;
      #pragma unroll
      for(int dy=0;dy<3;dy++){
        float rm = (dy==0)?R1:((dy==2)?R0:0.f);
        #pragma unroll
        for(int dx=0;dx<3;dx++){
          float cm = (dx==0)?C1:((dx==2)?C0:0.f);
          float corner = 0.f;
          if(dy==0&&dx==0)corner=cHW;
          if(dy==0&&dx==2)corner=cH0;
          if(dy==2&&dx==0)corner=c0W;
          if(dy==2&&dx==2)corner=c00;
          s += wp[dy*3+dx]*(T-rm-cm+corner);
        }
      }
    }
    avg[tid] = s*(1.f/16384.f);
  }
  __syncthreads();
  if(tid<24){
    float s = fc1b[tid];
    const float* w = fc1w + (size_t)tid*384;
    for(int c=0;c<384;c++) s += w[c]*avg[c];
    y1[tid] = fmaxf(s,0.f);
  }
  __syncthreads();
  {
    float s = fc2b[tid];
    const float* w = fc2w + (size_t)tid*24;
    #pragma unroll
    for(int j=0;j<24;j++) s += w[j]*y1[j];
    Lb[tid] = s/(1.f+__expf(-s));
  }
  __syncthreads();
  if(tid<48){
    const float* w = po1 + (size_t)tid*384;
    float s = 0.f;
    for(int c=0;c<384;c++) s += w[c]*Lb[c];
    constv[b*48+tid] = s;
  }
}

// per (b,h): sum Spart, normalize, softmax; m2o written FRAGMENT-MAJOR:
// addr = (((b*12+ck)*3+mt)*64 + quad*16+mrow)*8 + j  for (o=mt*16+mrow, hd=ck*32+quad*8+j)
__global__ __launch_bounds__(256) void k_attn(const float* __restrict__ Spart,
                                              const float* __restrict__ qn2,
                                              const float* __restrict__ temp,
                                              const float* __restrict__ po1,
                                              ushort_t* __restrict__ m2o){
  int h = blockIdx.x, b = blockIdx.y, tid = threadIdx.x;
  __shared__ float att[2304];
  __shared__ float nq[48], nk[48];
  const float* kn2 = qn2 + 1536;
  if(tid<48)      nq[tid]    = fmaxf(sqrtf(qn2[(size_t)b*D1 + h*48 + tid]),    1e-12f);
  else if(tid<96) nk[tid-48] = fmaxf(sqrtf(kn2[(size_t)b*D1 + h*48 + tid-48]), 1e-12f);
  __syncthreads();
  float tmp = temp[h];
  const float* Sp = Spart + ((size_t)(b*HEADS+h)*32)*2304;
  for(int idx=tid; idx<2304; idx+=256){
    float s = 0.f;
    for(int blk=0;blk<32;blk++) s += Sp[(size_t)blk*2304 + idx];
    int c = idx/48, d = idx - c*48;
    att[idx] = s*tmp/(nq[c]*nk[d]);
  }
  __syncthreads();
  if(tid<48){
    float* row = &att[tid*48];
    float m = -1e30f;
    for(int d=0;d<48;d++) m = fmaxf(m,row[d]);
    float s = 0.f;
    for(int d=0;d<48;d++){ float e=__expf(row[d]-m); row[d]=e; s+=e; }
    float inv = 1.f/s;
    for(int d=0;d<48;d++) row[d]*=inv;
  }
  __syncthreads();
  for(int idx=tid; idx<2304; idx+=256){
    int d = idx/48, o = idx - d*48;
    float s = 0.f;
    for(int c=0;c<48;c++) s += po1[(size_t)o*D1 + h*48 + c]*att[c*48+d];
    int hd = h*48 + d;
    int ck = hd>>5, rem = hd&31, quad = rem>>3, j = rem&7;
    int mt = o>>4, mrow = o&15;
    m2o[((((size_t)b*12 + ck)*3 + mt)*64 + quad*16 + mrow)*8 + j] = f2bf(s);
  }
}

// out = x + constv + M2 @ V via MFMA; 64 pos/block (1024 blocks = 4/CU),
// double-buffered LDS; Af loads coalesced via fragment-major m2o.
#define FROW2 40
__global__ __launch_bounds__(256,4) void k_final(const ushort_t* __restrict__ qkvd,
                                                 const ushort_t* __restrict__ m2o,
                                                 const float* __restrict__ constv,
                                                 const float* __restrict__ x,
                                                 float* __restrict__ out){
  __shared__ __align__(16) ushort_t vT[2][64*FROW2];   // 10240 B
  int tid = threadIdx.x;
  int wave = tid>>6, lane = tid&63;
  int quad = lane>>4, mrow = lane&15;
  int pos0 = blockIdx.x*64;
  int b = blockIdx.y;
  const ushort_t* vb = qkvd + ((size_t)b*1152 + 768)*HW + pos0;
  const ushort_t* AbF = m2o + (size_t)b*18432 + lane*8;
  f32x4 acc[3];
  #pragma unroll
  for(int mt=0;mt<3;mt++) acc[mt] = (f32x4){0.f,0.f,0.f,0.f};

  auto stage = [&](int ck, int buf){
    int ch = tid>>3, pg = tid&7, p0 = pg*8;   // 256 units = 32 ch x 8 pos-groups
    int chg = ch>>3, cl = ch&7;
    short8 v = *(const short8*)(vb + (size_t)(ck*32+ch)*HW + p0);
    ushort_t tmp[8]; *(short8*)tmp = v;
    #pragma unroll
    for(int i=0;i<8;i++){
      int p = p0+i;
      int sl = (chg ^ (p&3) ^ ((p>>3)&3)) & 3;
      vT[buf][p*FROW2 + (sl<<3) + cl] = tmp[i];
    }
  };
  stage(0,0);
  __syncthreads();
  for(int ck=0; ck<12; ck++){
    if(ck<11) stage(ck+1, (ck+1)&1);
    short8 Af[3], Bf;
    #pragma unroll
    for(int mt=0;mt<3;mt++)
      Af[mt] = *(const short8*)(AbF + (size_t)(ck*3 + mt)*512);
    {
      int p = wave*16 + mrow;
      int sl = (quad ^ (p&3) ^ ((p>>3)&3)) & 3;
      Bf = *(const short8*)(&vT[ck&1][p*FROW2 + (sl<<3)]);
    }
    #pragma unroll
    for(int mt=0;mt<3;mt++)
      acc[mt] = __builtin_amdgcn_mfma_f32_16x16x32_bf16(Af[mt], Bf, acc[mt], 0,0,0);
    __syncthreads();
  }
  const float* xb = x + (size_t)b*CC*HW + pos0;
  float* ob = out + (size_t)b*CC*HW + pos0;
  #pragma unroll
  for(int mt=0;mt<3;mt++){
    int p = wave*16 + mrow;
    #pragma unroll
    for(int r=0;r<4;r++){
      int o = mt*16 + quad*4 + r;
      ob[(size_t)o*HW + p] = xb[(size_t)o*HW + p] + constv[b*48+o] + acc[mt][r];
    }
  }
}

extern "C" void kernel_launch(void* const* d_in, const int* in_sizes, int n_in,
                              void* d_out, int out_size, void* d_ws, size_t ws_size,
                              hipStream_t stream){
  const float* x    = (const float*)d_in[0];
  const float* qw   = (const float*)d_in[1];
  const float* dw   = (const float*)d_in[2];
  const float* po1  = (const float*)d_in[3];
  const float* fc1w = (const float*)d_in[4];
  const float* fc1b = (const float*)d_in[5];
  const float* fc2w = (const float*)d_in[6];
  const float* fc2b = (const float*)d_in[7];
  const float* temp = (const float*)d_in[8];
  float* out = (float*)d_out;
  char* ws = (char*)d_ws;

  // workspace layout (~161.6 MB). xb16 ALIASES Spart (used in disjoint phases).
  ushort_t* qkvd   = (ushort_t*)(ws);                 // 150,994,944
  float*    Spart  = (float*)(ws + 150994944);        // 9,437,184
  ushort_t* xb16   = (ushort_t*)(ws + 150994944);     // 6,489,600 (alias of Spart)
  float*    qn2    = (float*)(ws + 160432128);        // 12,288 (qn2 + kn2)
  float*    xst    = (float*)(ws + 160444416);        // 6,912
  float*    constv = (float*)(ws + 160451328);        // 768
  ushort_t* m2o    = (ushort_t*)(ws + 160452096);     // 147,456 (frag-major [b][12][3][64][8])
  ushort_t* wfp    = (ushort_t*)(ws + 160599552);     // 1,032,192 (frag-major 32x32 [slice][28][4][64][8])

  k_wf    <<<dim3(1152),         256, 0, stream>>>(dw, qw, wfp, qn2);
  k_xpose <<<dim3(130,BB),       256, 0, stream>>>(x, xb16, xst);
  k_conv  <<<dim3(128,9,BB),     256, 0, stream>>>(xb16, wfp, qkvd);
  k_S     <<<dim3(32,HEADS,BB),  256, 0, stream>>>(qkvd, Spart, qn2);
  k_mlp   <<<dim3(BB),           384, 0, stream>>>(xst, qw, dw, fc1w, fc1b, fc2w, fc2b, po1, constv);
  k_attn  <<<dim3(HEADS,BB),     256, 0, stream>>>(Spart, qn2, temp, po1, m2o);
  k_final <<<dim3(256,BB),       256, 0, stream>>>(qkvd, m2o, constv, x, out);
}

// Round 18
// 296.230 us; speedup vs baseline: 1.0624x; 1.0624x over previous
//
#include <hip/hip_runtime.h>
#include <cstdint>

#define BB 4
#define CC 48
#define HW 16384
#define D1 384
#define HEADS 8

typedef unsigned short ushort_t;
typedef __attribute__((ext_vector_type(8))) short short8;
typedef __attribute__((ext_vector_type(4))) float f32x4;

__device__ __forceinline__ float bf2f(ushort_t u){
  union{uint32_t i; float f;} v; v.i = ((uint32_t)u)<<16; return v.f;
}
__device__ __forceinline__ ushort_t f2bf(float f){
  union{float f; uint32_t i;} v; v.f=f;
  uint32_t x = v.i;
  uint32_t r = (x + 0x7fff + ((x>>16)&1)) >> 16;
  return (ushort_t)r;
}

// fused-weight precompute in FRAGMENT-MAJOR layout (B-operand role):
// addr = ((((slice*2+mhalf)*14 + chunk)*4 + mt)*64 + quad*16 + mrow)*8 + j
// element (oc, kk): oc = slice*128 + mhalf*64 + mt*16 + mrow, kk = chunk*32 + quad*8 + j.
// Also zeroes qn2(3072)+xst(1728) = 4800 floats (contiguous).
__global__ __launch_bounds__(256) void k_wf(const float* __restrict__ dw,
                                            const float* __restrict__ qw,
                                            ushort_t* __restrict__ wfp,
                                            float* __restrict__ qn2){
  int oc = blockIdx.x, tid = threadIdx.x;
  if(oc < 19){ int i = oc*256 + tid; if(i < 4800) qn2[i] = 0.f; }
  int slice = oc>>7, oc128 = oc&127;
  int mhalf = oc128>>6, oc64 = oc128&63;
  int mt = oc64>>4, mrow = oc64&15;
  for(int kk=tid; kk<448; kk+=256){
    int t = kk/48, c = kk - t*48;
    float s = 0.f;
    if(t < 9){
      #pragma unroll
      for(int j=0;j<8;j++)
        s += dw[(size_t)oc*72 + j*9 + t] * qw[(size_t)((oc>>3)*8 + j)*48 + c];
    }
    int chunk = kk>>5, rem = kk&31, quad = rem>>3, j = rem&7;
    size_t addr = ((((size_t)(slice*2+mhalf)*14 + chunk)*4 + mt)*64 + quad*16 + mrow)*8 + j;
    wfp[addr] = f2bf(s);
  }
}

// x -> channel-last bf16 with 1-px zero border, FUSED with boundary-stats accumulation.
__global__ __launch_bounds__(256) void k_xpose(const float* __restrict__ x,
                                               ushort_t* __restrict__ xb16,
                                               float* __restrict__ xst){
  int gy = blockIdx.x;      // 0..129
  int b  = blockIdx.y;
  ushort_t* orow = xb16 + ((size_t)b*130 + gy)*130*48;
  int tid = threadIdx.x;
  if(gy==0 || gy==129){
    short8 z = {0,0,0,0,0,0,0,0};
    for(int u=tid; u<780; u+=256) *(short8*)(orow + u*8) = z;
    return;
  }
  __shared__ float xl[48*128];
  const float* xr = x + (size_t)b*CC*HW + (size_t)(gy-1)*128;
  for(int i=tid;i<6144;i+=256){
    int c=i>>7, p=i&127;
    xl[c*128+p] = xr[(size_t)c*HW + p];
  }
  __syncthreads();
  for(int u=tid; u<780; u+=256){
    int gx = u/6, s = u-gx*6;
    ushort_t tmp[8];
    if(gx==0||gx==129){
      #pragma unroll
      for(int j=0;j<8;j++) tmp[j]=0;
    } else {
      #pragma unroll
      for(int j=0;j<8;j++) tmp[j] = f2bf(xl[(s*8+j)*128 + (gx-1)]);
    }
    *(short8*)(orow + (size_t)u*8) = *(short8*)tmp;
  }
  if(tid < 48){
    const float* row = &xl[tid*128];
    float a0=0,a1=0,a2=0,a3=0;
    #pragma unroll 8
    for(int p=0;p<128;p+=4){ a0+=row[p]; a1+=row[p+1]; a2+=row[p+2]; a3+=row[p+3]; }
    float s = (a0+a1)+(a2+a3);
    float* o = xst + ((size_t)b*48 + tid)*9;
    atomicAdd(&o[0], s);
    atomicAdd(&o[3], row[0]);
    atomicAdd(&o[4], row[127]);
    if(gy==1)  { o[1]=s; o[5]=row[0]; o[6]=row[127]; }
    if(gy==128){ o[2]=s; o[7]=row[0]; o[8]=row[127]; }
  }
}

// dense 3x3 conv 48->1152 as MFMA GEMM; EXACT round-14 config (112 us measured):
// (256,3) + A-prefetch double-buffer; (256,4) spills (r9/r12/r15 evidence).
// 16x16x32 with 4x4 tile is the measured optimum (32x32x16 regressed: r17).
#define HROWC 64
__global__ __launch_bounds__(256,3) void k_conv(const ushort_t* __restrict__ xb16,
                                                const ushort_t* __restrict__ wfp,
                                                ushort_t* __restrict__ qkvd){
  __shared__ __align__(16) ushort_t xs[180*HROWC];   // 23040 B
  int tid  = threadIdx.x;
  int wave = tid>>6, lane = tid&63;
  int quad = lane>>4, mrow = lane&15;
  int mhalf = wave>>1, nhalf = wave&1;
  int tile = blockIdx.x;              // 128 tiles: 16 (y) x 8 (x)
  int ty0 = (tile>>3)*8, tx0 = (tile&7)*16;
  int ocb = blockIdx.y*128 + mhalf*64;
  int b   = blockIdx.z;

  // ---- staging: 8 independent loads in flight, then predicated LDS writes ----
  {
    const ushort_t* xh = xb16 + ((size_t)b*16900 + (size_t)ty0*130 + tx0)*48;
    short8 vbuf[8];
    #pragma unroll
    for(int i=0;i<8;i++){
      int u = tid + i*256;
      int uu = (u < 1944) ? u : 1943;
      int r = uu/6, g = uu - r*6;
      int hy = r/18, hx = r - hy*18;
      vbuf[i] = *(const short8*)(xh + ((size_t)hy*130 + hx)*48 + g*8);
    }
    #pragma unroll
    for(int i=0;i<8;i++){
      int u = tid + i*256;
      if(u < 1944){
        int r = u/6, g = u - r*6;
        *(short8*)(xs + r*HROWC + ((g ^ (r&7))<<3)) = vbuf[i];
      }
    }
  }
  __syncthreads();

  int rb[4];
  #pragma unroll
  for(int nt=0;nt<4;nt++) rb[nt] = (nhalf*4+nt+1)*18 + mrow + 1;

  const ushort_t* AbF = wfp + ((size_t)(blockIdx.y*2 + mhalf)*14*4)*512 + lane*8;
  f32x4 Cacc[4][4];
  #pragma unroll
  for(int mt=0;mt<4;mt++)
    #pragma unroll
    for(int nt=0;nt<4;nt++) Cacc[mt][nt] = (f32x4){0.f,0.f,0.f,0.f};

  short8 Ac[4], An[4];
  #pragma unroll
  for(int mt=0;mt<4;mt++) Ac[mt] = *(const short8*)(AbF + (size_t)mt*512);

  #pragma unroll
  for(int chunk=0; chunk<14; chunk++){
    if(chunk < 13){
      #pragma unroll
      for(int mt=0;mt<4;mt++)
        An[mt] = *(const short8*)(AbF + (size_t)((chunk+1)*4 + mt)*512);
    }
    int kq = chunk*32 + quad*8;
    int t  = kq/48;
    int c  = kq - t*48;
    int tc = (t<9) ? t : 8;            // weights are zero for t=9; halo junk harmless
    int dyq = tc/3;
    int drow = dyq*18 + (tc - dyq*3) - 19;
    int g = c>>3;
    short8 Bf[4];
    #pragma unroll
    for(int nt=0;nt<4;nt++){
      int r = rb[nt] + drow;
      Bf[nt] = *(const short8*)(xs + r*HROWC + ((g ^ (r&7))<<3));
    }
    // operand swap: C[m=px][n=oc] = halo^T-frag x weight-frag
    #pragma unroll
    for(int mt=0;mt<4;mt++)
      #pragma unroll
      for(int nt=0;nt<4;nt++)
        Cacc[mt][nt] = __builtin_amdgcn_mfma_f32_16x16x32_bf16(Bf[nt], Ac[mt], Cacc[mt][nt], 0,0,0);
    #pragma unroll
    for(int mt=0;mt<4;mt++) Ac[mt] = An[mt];
  }

  // ---- epilogue: lane holds 4 consecutive px at fixed oc -> one b64 store each ----
  #pragma unroll
  for(int mt=0;mt<4;mt++){
    int oc = ocb + mt*16 + mrow;
    ushort_t* orow = qkvd + ((size_t)b*1152 + oc)*HW;
    #pragma unroll
    for(int nt=0;nt<4;nt++){
      int py = nhalf*4 + nt;
      int gpos = (ty0+py)*128 + tx0 + quad*4;
      ushort_t pk[4];
      #pragma unroll
      for(int r=0;r<4;r++) pk[r] = f2bf(Cacc[mt][nt][r]);
      *(uint2*)(orow + gpos) = *(uint2*)pk;
    }
  }
}

// S = Q K^T per (b,h) via MFMA; norms free as diag(Q Q^T), diag(K K^T).
__global__ __launch_bounds__(256,3) void k_S(const ushort_t* __restrict__ qkvd,
                                             float* __restrict__ Spart,
                                             float* __restrict__ qn2){
  __shared__ __align__(16) ushort_t qk[96*264];   // 50688 B
  int tid = threadIdx.x;
  int blk = blockIdx.x, h = blockIdx.y, b = blockIdx.z;
  int wave = tid>>6, lane = tid&63;
  int quad = lane>>4, mrow = lane&15;
  const ushort_t* qb = qkvd + ((size_t)b*1152 + h*48)*HW;
  const ushort_t* kb = qb + (size_t)384*HW;

  f32x4 accS[3][3], accq[3], acck[3];
  #pragma unroll
  for(int mt=0;mt<3;mt++){
    accq[mt] = (f32x4){0.f,0.f,0.f,0.f};
    acck[mt] = (f32x4){0.f,0.f,0.f,0.f};
    #pragma unroll
    for(int nt=0;nt<3;nt++) accS[mt][nt] = (f32x4){0.f,0.f,0.f,0.f};
  }

  for(int half=0; half<2; half++){
    int p0 = blk*512 + half*256;
    __syncthreads();
    for(int u=tid; u<3072; u+=256){            // 96 ch x 32 b128-units
      int ch = u>>5, px = u&31;
      const ushort_t* src = ((ch<48) ? qb + (size_t)ch*HW
                                     : kb + (size_t)(ch-48)*HW) + p0 + px*8;
      *(short8*)(qk + ch*264 + px*8) = *(const short8*)src;
    }
    __syncthreads();
    #pragma unroll
    for(int ks=0; ks<2; ks++){
      int koff = wave*64 + ks*32 + quad*8;
      short8 Aq[3], Bk[3];
      #pragma unroll
      for(int mt=0;mt<3;mt++) Aq[mt] = *(const short8*)(qk + (mt*16+mrow)*264 + koff);
      #pragma unroll
      for(int nt=0;nt<3;nt++) Bk[nt] = *(const short8*)(qk + (48+nt*16+mrow)*264 + koff);
      #pragma unroll
      for(int mt=0;mt<3;mt++){
        accq[mt] = __builtin_amdgcn_mfma_f32_16x16x32_bf16(Aq[mt], Aq[mt], accq[mt], 0,0,0);
        acck[mt] = __builtin_amdgcn_mfma_f32_16x16x32_bf16(Bk[mt], Bk[mt], acck[mt], 0,0,0);
        #pragma unroll
        for(int nt=0;nt<3;nt++)
          accS[mt][nt] = __builtin_amdgcn_mfma_f32_16x16x32_bf16(Aq[mt], Bk[nt], accS[mt][nt], 0,0,0);
      }
    }
  }
  __syncthreads();
  float* scr = (float*)qk;
  #pragma unroll
  for(int mt=0;mt<3;mt++)
    #pragma unroll
    for(int nt=0;nt<3;nt++)
      #pragma unroll
      for(int r=0;r<4;r++)
        scr[wave*2304 + (mt*16+quad*4+r)*48 + nt*16 + mrow] = accS[mt][nt][r];
  __syncthreads();
  float* outp = Spart + ((size_t)((b*HEADS+h)*32 + blk))*2304;
  for(int idx=tid; idx<2304; idx+=256)
    outp[idx] = scr[idx] + scr[2304+idx] + scr[4608+idx] + scr[6912+idx];
  int rr = mrow - (quad<<2);
  #pragma unroll
  for(int r=0;r<4;r++){
    if(rr == r){
      #pragma unroll
      for(int mt=0;mt<3;mt++){
        atomicAdd(qn2 + (size_t)b*D1 + h*48 + mt*16 + mrow, accq[mt][r]);
        atomicAdd(qn2 + 1536 + (size_t)b*D1 + h*48 + mt*16 + mrow, acck[mt][r]);
      }
    }
  }
}

// per b: l-stats from x-stats -> mean -> fc1 -> relu -> fc2 -> swish -> constv = po1@L
__global__ __launch_bounds__(384) void k_mlp(const float* __restrict__ xst,
                                             const float* __restrict__ qw,
                                             const float* __restrict__ dw,
                                             const float* __restrict__ fc1w,
                                             const float* __restrict__ fc1b,
                                             const float* __restrict__ fc2w,
                                             const float* __restrict__ fc2b,
                                             const float* __restrict__ po1,
                                             float* __restrict__ constv){
  int b = blockIdx.x, tid = threadIdx.x;
  __shared__ float xsl[432];
  __shared__ float lst[3456];
  __shared__ float avg[384];
  __shared__ float y1[24];
  __shared__ float Lb[384];
  for(int i=tid;i<432;i+=384) xsl[i] = xst[(size_t)b*432 + i];
  __syncthreads();
  {
    float st[9];
    #pragma unroll
    for(int s=0;s<9;s++) st[s]=0.f;
    const float* w = qw + (size_t)(1152+tid)*48;
    for(int c=0;c<48;c++){
      float wv = w[c];
      #pragma unroll
      for(int s=0;s<9;s++) st[s] += wv*xsl[c*9+s];
    }
    #pragma unroll
    for(int s=0;s<9;s++) lst[tid*9+s] = st[s];
  }
  __syncthreads();
  {
    int base = tid & ~7;
    const float* ls = &lst[base*9];
    float s = 0.f;
    #pragma unroll
    for(int i=0;i<8;i++){
      float T=ls[i*9+0],R0=ls[i*9+1],R1=ls[i*9+2],C0=ls[i*9+3],C1=ls[i*9+4];
      float c00=ls[i*9+5],c0W=ls[i*9+6],cH0=ls[i*9+7],cHW=ls[i*9+8];
      const float* wp = dw + (size_t)(1152+tid)*72 + i*9;
      #pragma unroll
      for(int dy=0;dy<3;dy++){
        float rm = (dy==0)?R1:((dy==2)?R0:0.f);
        #pragma unroll
        for(int dx=0;dx<3;dx++){
          float cm = (dx==0)?C1:((dx==2)?C0:0.f);
          float corner = 0.f;
          if(dy==0&&dx==0)corner=cHW;
          if(dy==0&&dx==2)corner=cH0;
          if(dy==2&&dx==0)corner=c0W;
          if(dy==2&&dx==2)corner=c00;
          s += wp[dy*3+dx]*(T-rm-cm+corner);
        }
      }
    }
    avg[tid] = s*(1.f/16384.f);
  }
  __syncthreads();
  if(tid<24){
    float s = fc1b[tid];
    const float* w = fc1w + (size_t)tid*384;
    for(int c=0;c<384;c++) s += w[c]*avg[c];
    y1[tid] = fmaxf(s,0.f);
  }
  __syncthreads();
  {
    float s = fc2b[tid];
    const float* w = fc2w + (size_t)tid*24;
    #pragma unroll
    for(int j=0;j<24;j++) s += w[j]*y1[j];
    Lb[tid] = s/(1.f+__expf(-s));
  }
  __syncthreads();
  if(tid<48){
    const float* w = po1 + (size_t)tid*384;
    float s = 0.f;
    for(int c=0;c<384;c++) s += w[c]*Lb[c];
    constv[b*48+tid] = s;
  }
}

// per (b,h): sum Spart, normalize, softmax; m2o written FRAGMENT-MAJOR:
// addr = (((b*12+ck)*3+mt)*64 + quad*16+mrow)*8 + j  for (o=mt*16+mrow, hd=ck*32+quad*8+j)
__global__ __launch_bounds__(256) void k_attn(const float* __restrict__ Spart,
                                              const float* __restrict__ qn2,
                                              const float* __restrict__ temp,
                                              const float* __restrict__ po1,
                                              ushort_t* __restrict__ m2o){
  int h = blockIdx.x, b = blockIdx.y, tid = threadIdx.x;
  __shared__ float att[2304];
  __shared__ float nq[48], nk[48];
  const float* kn2 = qn2 + 1536;
  if(tid<48)      nq[tid]    = fmaxf(sqrtf(qn2[(size_t)b*D1 + h*48 + tid]),    1e-12f);
  else if(tid<96) nk[tid-48] = fmaxf(sqrtf(kn2[(size_t)b*D1 + h*48 + tid-48]), 1e-12f);
  __syncthreads();
  float tmp = temp[h];
  const float* Sp = Spart + ((size_t)(b*HEADS+h)*32)*2304;
  for(int idx=tid; idx<2304; idx+=256){
    float s = 0.f;
    for(int blk=0;blk<32;blk++) s += Sp[(size_t)blk*2304 + idx];
    int c = idx/48, d = idx - c*48;
    att[idx] = s*tmp/(nq[c]*nk[d]);
  }
  __syncthreads();
  if(tid<48){
    float* row = &att[tid*48];
    float m = -1e30f;
    for(int d=0;d<48;d++) m = fmaxf(m,row[d]);
    float s = 0.f;
    for(int d=0;d<48;d++){ float e=__expf(row[d]-m); row[d]=e; s+=e; }
    float inv = 1.f/s;
    for(int d=0;d<48;d++) row[d]*=inv;
  }
  __syncthreads();
  for(int idx=tid; idx<2304; idx+=256){
    int d = idx/48, o = idx - d*48;
    float s = 0.f;
    for(int c=0;c<48;c++) s += po1[(size_t)o*D1 + h*48 + c]*att[c*48+d];
    int hd = h*48 + d;
    int ck = hd>>5, rem = hd&31, quad = rem>>3, j = rem&7;
    int mt = o>>4, mrow = o&15;
    m2o[((((size_t)b*12 + ck)*3 + mt)*64 + quad*16 + mrow)*8 + j] = f2bf(s);
  }
}

// out = x + constv + M2 @ V via MFMA; 64 pos/block (1024 blocks = 4/CU),
// double-buffered LDS; Af loads coalesced via fragment-major m2o.
#define FROW2 40
__global__ __launch_bounds__(256,4) void k_final(const ushort_t* __restrict__ qkvd,
                                                 const ushort_t* __restrict__ m2o,
                                                 const float* __restrict__ constv,
                                                 const float* __restrict__ x,
                                                 float* __restrict__ out){
  __shared__ __align__(16) ushort_t vT[2][64*FROW2];   // 10240 B
  int tid = threadIdx.x;
  int wave = tid>>6, lane = tid&63;
  int quad = lane>>4, mrow = lane&15;
  int pos0 = blockIdx.x*64;
  int b = blockIdx.y;
  const ushort_t* vb = qkvd + ((size_t)b*1152 + 768)*HW + pos0;
  const ushort_t* AbF = m2o + (size_t)b*18432 + lane*8;
  f32x4 acc[3];
  #pragma unroll
  for(int mt=0;mt<3;mt++) acc[mt] = (f32x4){0.f,0.f,0.f,0.f};

  auto stage = [&](int ck, int buf){
    int ch = tid>>3, pg = tid&7, p0 = pg*8;   // 256 units = 32 ch x 8 pos-groups
    int chg = ch>>3, cl = ch&7;
    short8 v = *(const short8*)(vb + (size_t)(ck*32+ch)*HW + p0);
    ushort_t tmp[8]; *(short8*)tmp = v;
    #pragma unroll
    for(int i=0;i<8;i++){
      int p = p0+i;
      int sl = (chg ^ (p&3) ^ ((p>>3)&3)) & 3;
      vT[buf][p*FROW2 + (sl<<3) + cl] = tmp[i];
    }
  };
  stage(0,0);
  __syncthreads();
  for(int ck=0; ck<12; ck++){
    if(ck<11) stage(ck+1, (ck+1)&1);
    short8 Af[3], Bf;
    #pragma unroll
    for(int mt=0;mt<3;mt++)
      Af[mt] = *(const short8*)(AbF + (size_t)(ck*3 + mt)*512);
    {
      int p = wave*16 + mrow;
      int sl = (quad ^ (p&3) ^ ((p>>3)&3)) & 3;
      Bf = *(const short8*)(&vT[ck&1][p*FROW2 + (sl<<3)]);
    }
    #pragma unroll
    for(int mt=0;mt<3;mt++)
      acc[mt] = __builtin_amdgcn_mfma_f32_16x16x32_bf16(Af[mt], Bf, acc[mt], 0,0,0);
    __syncthreads();
  }
  const float* xb = x + (size_t)b*CC*HW + pos0;
  float* ob = out + (size_t)b*CC*HW + pos0;
  #pragma unroll
  for(int mt=0;mt<3;mt++){
    int p = wave*16 + mrow;
    #pragma unroll
    for(int r=0;r<4;r++){
      int o = mt*16 + quad*4 + r;
      ob[(size_t)o*HW + p] = xb[(size_t)o*HW + p] + constv[b*48+o] + acc[mt][r];
    }
  }
}

extern "C" void kernel_launch(void* const* d_in, const int* in_sizes, int n_in,
                              void* d_out, int out_size, void* d_ws, size_t ws_size,
                              hipStream_t stream){
  const float* x    = (const float*)d_in[0];
  const float* qw   = (const float*)d_in[1];
  const float* dw   = (const float*)d_in[2];
  const float* po1  = (const float*)d_in[3];
  const float* fc1w = (const float*)d_in[4];
  const float* fc1b = (const float*)d_in[5];
  const float* fc2w = (const float*)d_in[6];
  const float* fc2b = (const float*)d_in[7];
  const float* temp = (const float*)d_in[8];
  float* out = (float*)d_out;
  char* ws = (char*)d_ws;

  // workspace layout (~161.6 MB). xb16 ALIASES Spart (used in disjoint phases).
  ushort_t* qkvd   = (ushort_t*)(ws);                 // 150,994,944
  float*    Spart  = (float*)(ws + 150994944);        // 9,437,184
  ushort_t* xb16   = (ushort_t*)(ws + 150994944);     // 6,489,600 (alias of Spart)
  float*    qn2    = (float*)(ws + 160432128);        // 12,288 (qn2 + kn2)
  float*    xst    = (float*)(ws + 160444416);        // 6,912
  float*    constv = (float*)(ws + 160451328);        // 768
  ushort_t* m2o    = (ushort_t*)(ws + 160452096);     // 147,456 (frag-major [b][12][3][64][8])
  ushort_t* wfp    = (ushort_t*)(ws + 160599552);     // 1,032,192 (frag-major)

  k_wf    <<<dim3(1152),         256, 0, stream>>>(dw, qw, wfp, qn2);
  k_xpose <<<dim3(130,BB),       256, 0, stream>>>(x, xb16, xst);
  k_conv  <<<dim3(128,9,BB),     256, 0, stream>>>(xb16, wfp, qkvd);
  k_S     <<<dim3(32,HEADS,BB),  256, 0, stream>>>(qkvd, Spart, qn2);
  k_mlp   <<<dim3(BB),           384, 0, stream>>>(xst, qw, dw, fc1w, fc1b, fc2w, fc2b, po1, constv);
  k_attn  <<<dim3(HEADS,BB),     256, 0, stream>>>(Spart, qn2, temp, po1, m2o);
  k_final <<<dim3(256,BB),       256, 0, stream>>>(qkvd, m2o, constv, x, out);
}

// Round 19
// 286.388 us; speedup vs baseline: 1.0989x; 1.0344x over previous
//
#include <hip/hip_runtime.h>
#include <cstdint>

#define BB 4
#define CC 48
#define HW 16384
#define D1 384
#define HEADS 8

typedef unsigned short ushort_t;
typedef __attribute__((ext_vector_type(8))) short short8;
typedef __attribute__((ext_vector_type(4))) float f32x4;

__device__ __forceinline__ float bf2f(ushort_t u){
  union{uint32_t i; float f;} v; v.i = ((uint32_t)u)<<16; return v.f;
}
__device__ __forceinline__ ushort_t f2bf(float f){
  union{float f; uint32_t i;} v; v.f=f;
  uint32_t x = v.i;
  uint32_t r = (x + 0x7fff + ((x>>16)&1)) >> 16;
  return (ushort_t)r;
}

// fused-weight precompute in FRAGMENT-MAJOR layout (B-operand role):
// addr = ((((slice*2+mhalf)*14 + chunk)*4 + mt)*64 + quad*16 + mrow)*8 + j
// Also zeroes qn2(3072)+xst(1728) = 4800 floats (contiguous).
__global__ __launch_bounds__(256) void k_wf(const float* __restrict__ dw,
                                            const float* __restrict__ qw,
                                            ushort_t* __restrict__ wfp,
                                            float* __restrict__ qn2){
  int oc = blockIdx.x, tid = threadIdx.x;
  if(oc < 19){ int i = oc*256 + tid; if(i < 4800) qn2[i] = 0.f; }
  int slice = oc>>7, oc128 = oc&127;
  int mhalf = oc128>>6, oc64 = oc128&63;
  int mt = oc64>>4, mrow = oc64&15;
  for(int kk=tid; kk<448; kk+=256){
    int t = kk/48, c = kk - t*48;
    float s = 0.f;
    if(t < 9){
      #pragma unroll
      for(int j=0;j<8;j++)
        s += dw[(size_t)oc*72 + j*9 + t] * qw[(size_t)((oc>>3)*8 + j)*48 + c];
    }
    int chunk = kk>>5, rem = kk&31, quad = rem>>3, j = rem&7;
    size_t addr = ((((size_t)(slice*2+mhalf)*14 + chunk)*4 + mt)*64 + quad*16 + mrow)*8 + j;
    wfp[addr] = f2bf(s);
  }
}

// x -> channel-last bf16 with 1-px zero border, FUSED with boundary-stats accumulation.
__global__ __launch_bounds__(256) void k_xpose(const float* __restrict__ x,
                                               ushort_t* __restrict__ xb16,
                                               float* __restrict__ xst){
  int gy = blockIdx.x;      // 0..129
  int b  = blockIdx.y;
  ushort_t* orow = xb16 + ((size_t)b*130 + gy)*130*48;
  int tid = threadIdx.x;
  if(gy==0 || gy==129){
    short8 z = {0,0,0,0,0,0,0,0};
    for(int u=tid; u<780; u+=256) *(short8*)(orow + u*8) = z;
    return;
  }
  __shared__ float xl[48*128];
  const float* xr = x + (size_t)b*CC*HW + (size_t)(gy-1)*128;
  for(int i=tid;i<6144;i+=256){
    int c=i>>7, p=i&127;
    xl[c*128+p] = xr[(size_t)c*HW + p];
  }
  __syncthreads();
  for(int u=tid; u<780; u+=256){
    int gx = u/6, s = u-gx*6;
    ushort_t tmp[8];
    if(gx==0||gx==129){
      #pragma unroll
      for(int j=0;j<8;j++) tmp[j]=0;
    } else {
      #pragma unroll
      for(int j=0;j<8;j++) tmp[j] = f2bf(xl[(s*8+j)*128 + (gx-1)]);
    }
    *(short8*)(orow + (size_t)u*8) = *(short8*)tmp;
  }
  if(tid < 48){
    const float* row = &xl[tid*128];
    float a0=0,a1=0,a2=0,a3=0;
    #pragma unroll 8
    for(int p=0;p<128;p+=4){ a0+=row[p]; a1+=row[p+1]; a2+=row[p+2]; a3+=row[p+3]; }
    float s = (a0+a1)+(a2+a3);
    float* o = xst + ((size_t)b*48 + tid)*9;
    atomicAdd(&o[0], s);
    atomicAdd(&o[3], row[0]);
    atomicAdd(&o[4], row[127]);
    if(gy==1)  { o[1]=s; o[5]=row[0]; o[6]=row[127]; }
    if(gy==128){ o[2]=s; o[7]=row[0]; o[8]=row[127]; }
  }
}

// dense 3x3 conv 48->1152 as MFMA GEMM; r14 config + B-fragment (LDS) prefetch
// one chunk ahead (mirrors the A prefetch). ~152 regs <= 170 cap at (256,3).
#define HROWC 64
__global__ __launch_bounds__(256,3) void k_conv(const ushort_t* __restrict__ xb16,
                                                const ushort_t* __restrict__ wfp,
                                                ushort_t* __restrict__ qkvd){
  __shared__ __align__(16) ushort_t xs[180*HROWC];   // 23040 B
  int tid  = threadIdx.x;
  int wave = tid>>6, lane = tid&63;
  int quad = lane>>4, mrow = lane&15;
  int mhalf = wave>>1, nhalf = wave&1;
  int tile = blockIdx.x;              // 128 tiles: 16 (y) x 8 (x)
  int ty0 = (tile>>3)*8, tx0 = (tile&7)*16;
  int ocb = blockIdx.y*128 + mhalf*64;
  int b   = blockIdx.z;

  // ---- staging: 8 independent loads in flight, then predicated LDS writes ----
  {
    const ushort_t* xh = xb16 + ((size_t)b*16900 + (size_t)ty0*130 + tx0)*48;
    short8 vbuf[8];
    #pragma unroll
    for(int i=0;i<8;i++){
      int u = tid + i*256;
      int uu = (u < 1944) ? u : 1943;
      int r = uu/6, g = uu - r*6;
      int hy = r/18, hx = r - hy*18;
      vbuf[i] = *(const short8*)(xh + ((size_t)hy*130 + hx)*48 + g*8);
    }
    #pragma unroll
    for(int i=0;i<8;i++){
      int u = tid + i*256;
      if(u < 1944){
        int r = u/6, g = u - r*6;
        *(short8*)(xs + r*HROWC + ((g ^ (r&7))<<3)) = vbuf[i];
      }
    }
  }
  __syncthreads();

  int rb[4];
  #pragma unroll
  for(int nt=0;nt<4;nt++) rb[nt] = (nhalf*4+nt+1)*18 + mrow + 1;

  const ushort_t* AbF = wfp + ((size_t)(blockIdx.y*2 + mhalf)*14*4)*512 + lane*8;
  f32x4 Cacc[4][4];
  #pragma unroll
  for(int mt=0;mt<4;mt++)
    #pragma unroll
    for(int nt=0;nt<4;nt++) Cacc[mt][nt] = (f32x4){0.f,0.f,0.f,0.f};

  auto loadB = [&](int chunk, short8* Bf){
    int kq = chunk*32 + quad*8;
    int t  = kq/48;
    int c  = kq - t*48;
    int tc = (t<9) ? t : 8;            // weights zero for t=9; halo junk harmless
    int dyq = tc/3;
    int drow = dyq*18 + (tc - dyq*3) - 19;
    int g = c>>3;
    #pragma unroll
    for(int nt=0;nt<4;nt++){
      int r = rb[nt] + drow;
      Bf[nt] = *(const short8*)(xs + r*HROWC + ((g ^ (r&7))<<3));
    }
  };

  short8 Ac[4], An[4], Bc[4], Bn[4];
  #pragma unroll
  for(int mt=0;mt<4;mt++) Ac[mt] = *(const short8*)(AbF + (size_t)mt*512);
  loadB(0, Bc);

  #pragma unroll
  for(int chunk=0; chunk<14; chunk++){
    if(chunk < 13){
      #pragma unroll
      for(int mt=0;mt<4;mt++)
        An[mt] = *(const short8*)(AbF + (size_t)((chunk+1)*4 + mt)*512);
      loadB(chunk+1, Bn);
    }
    // operand swap: C[m=px][n=oc] = halo^T-frag x weight-frag
    #pragma unroll
    for(int mt=0;mt<4;mt++)
      #pragma unroll
      for(int nt=0;nt<4;nt++)
        Cacc[mt][nt] = __builtin_amdgcn_mfma_f32_16x16x32_bf16(Bc[nt], Ac[mt], Cacc[mt][nt], 0,0,0);
    #pragma unroll
    for(int mt=0;mt<4;mt++){ Ac[mt] = An[mt]; Bc[mt] = Bn[mt]; }
  }

  // ---- epilogue: lane holds 4 consecutive px at fixed oc -> one b64 store each ----
  #pragma unroll
  for(int mt=0;mt<4;mt++){
    int oc = ocb + mt*16 + mrow;
    ushort_t* orow = qkvd + ((size_t)b*1152 + oc)*HW;
    #pragma unroll
    for(int nt=0;nt<4;nt++){
      int py = nhalf*4 + nt;
      int gpos = (ty0+py)*128 + tx0 + quad*4;
      ushort_t pk[4];
      #pragma unroll
      for(int r=0;r<4;r++) pk[r] = f2bf(Cacc[mt][nt][r]);
      *(uint2*)(orow + gpos) = *(uint2*)pk;
    }
  }
}

// S = Q K^T per (b,h) via MFMA; norms free as diag(Q Q^T), diag(K K^T).
__global__ __launch_bounds__(256,3) void k_S(const ushort_t* __restrict__ qkvd,
                                             float* __restrict__ Spart,
                                             float* __restrict__ qn2){
  __shared__ __align__(16) ushort_t qk[96*264];   // 50688 B
  int tid = threadIdx.x;
  int blk = blockIdx.x, h = blockIdx.y, b = blockIdx.z;
  int wave = tid>>6, lane = tid&63;
  int quad = lane>>4, mrow = lane&15;
  const ushort_t* qb = qkvd + ((size_t)b*1152 + h*48)*HW;
  const ushort_t* kb = qb + (size_t)384*HW;

  f32x4 accS[3][3], accq[3], acck[3];
  #pragma unroll
  for(int mt=0;mt<3;mt++){
    accq[mt] = (f32x4){0.f,0.f,0.f,0.f};
    acck[mt] = (f32x4){0.f,0.f,0.f,0.f};
    #pragma unroll
    for(int nt=0;nt<3;nt++) accS[mt][nt] = (f32x4){0.f,0.f,0.f,0.f};
  }

  for(int half=0; half<2; half++){
    int p0 = blk*512 + half*256;
    __syncthreads();
    for(int u=tid; u<3072; u+=256){            // 96 ch x 32 b128-units
      int ch = u>>5, px = u&31;
      const ushort_t* src = ((ch<48) ? qb + (size_t)ch*HW
                                     : kb + (size_t)(ch-48)*HW) + p0 + px*8;
      *(short8*)(qk + ch*264 + px*8) = *(const short8*)src;
    }
    __syncthreads();
    #pragma unroll
    for(int ks=0; ks<2; ks++){
      int koff = wave*64 + ks*32 + quad*8;
      short8 Aq[3], Bk[3];
      #pragma unroll
      for(int mt=0;mt<3;mt++) Aq[mt] = *(const short8*)(qk + (mt*16+mrow)*264 + koff);
      #pragma unroll
      for(int nt=0;nt<3;nt++) Bk[nt] = *(const short8*)(qk + (48+nt*16+mrow)*264 + koff);
      #pragma unroll
      for(int mt=0;mt<3;mt++){
        accq[mt] = __builtin_amdgcn_mfma_f32_16x16x32_bf16(Aq[mt], Aq[mt], accq[mt], 0,0,0);
        acck[mt] = __builtin_amdgcn_mfma_f32_16x16x32_bf16(Bk[mt], Bk[mt], acck[mt], 0,0,0);
        #pragma unroll
        for(int nt=0;nt<3;nt++)
          accS[mt][nt] = __builtin_amdgcn_mfma_f32_16x16x32_bf16(Aq[mt], Bk[nt], accS[mt][nt], 0,0,0);
      }
    }
  }
  __syncthreads();
  float* scr = (float*)qk;
  #pragma unroll
  for(int mt=0;mt<3;mt++)
    #pragma unroll
    for(int nt=0;nt<3;nt++)
      #pragma unroll
      for(int r=0;r<4;r++)
        scr[wave*2304 + (mt*16+quad*4+r)*48 + nt*16 + mrow] = accS[mt][nt][r];
  __syncthreads();
  float* outp = Spart + ((size_t)((b*HEADS+h)*32 + blk))*2304;
  for(int idx=tid; idx<2304; idx+=256)
    outp[idx] = scr[idx] + scr[2304+idx] + scr[4608+idx] + scr[6912+idx];
  int rr = mrow - (quad<<2);
  #pragma unroll
  for(int r=0;r<4;r++){
    if(rr == r){
      #pragma unroll
      for(int mt=0;mt<3;mt++){
        atomicAdd(qn2 + (size_t)b*D1 + h*48 + mt*16 + mrow, accq[mt][r]);
        atomicAdd(qn2 + 1536 + (size_t)b*D1 + h*48 + mt*16 + mrow, acck[mt][r]);
      }
    }
  }
}

// reduce Spart over 32 blocks -> Sred[bh][2304]; 288 blocks, coalesced
__global__ __launch_bounds__(256) void k_sred(const float* __restrict__ Spart,
                                              float* __restrict__ sred){
  int idx = blockIdx.x*256 + threadIdx.x;   // 73728 total
  int bh = idx/2304, e = idx - bh*2304;
  const float* p = Spart + (size_t)bh*32*2304 + e;
  float s = 0.f;
  #pragma unroll
  for(int blk=0; blk<32; blk++) s += p[(size_t)blk*2304];
  sred[idx] = s;
}

// per b: l-stats from x-stats -> mean -> fc1 -> relu -> fc2 -> swish -> constv = po1@L
__global__ __launch_bounds__(384) void k_mlp(const float* __restrict__ xst,
                                             const float* __restrict__ qw,
                                             const float* __restrict__ dw,
                                             const float* __restrict__ fc1w,
                                             const float* __restrict__ fc1b,
                                             const float* __restrict__ fc2w,
                                             const float* __restrict__ fc2b,
                                             const float* __restrict__ po1,
                                             float* __restrict__ constv){
  int b = blockIdx.x, tid = threadIdx.x;
  __shared__ float xsl[432];
  __shared__ float lst[3456];
  __shared__ float avg[384];
  __shared__ float y1[24];
  __shared__ float Lb[384];
  for(int i=tid;i<432;i+=384) xsl[i] = xst[(size_t)b*432 + i];
  __syncthreads();
  {
    float st[9];
    #pragma unroll
    for(int s=0;s<9;s++) st[s]=0.f;
    const float* w = qw + (size_t)(1152+tid)*48;
    for(int c=0;c<48;c++){
      float wv = w[c];
      #pragma unroll
      for(int s=0;s<9;s++) st[s] += wv*xsl[c*9+s];
    }
    #pragma unroll
    for(int s=0;s<9;s++) lst[tid*9+s] = st[s];
  }
  __syncthreads();
  {
    int base = tid & ~7;
    const float* ls = &lst[base*9];
    float s = 0.f;
    #pragma unroll
    for(int i=0;i<8;i++){
      float T=ls[i*9+0],R0=ls[i*9+1],R1=ls[i*9+2],C0=ls[i*9+3],C1=ls[i*9+4];
      float c00=ls[i*9+5],c0W=ls[i*9+6],cH0=ls[i*9+7],cHW=ls[i*9+8];
      const float* wp = dw + (size_t)(1152+tid)*72 + i*9;
      #pragma unroll
      for(int dy=0;dy<3;dy++){
        float rm = (dy==0)?R1:((dy==2)?R0:0.f);
        #pragma unroll
        for(int dx=0;dx<3;dx++){
          float cm = (dx==0)?C1:((dx==2)?C0:0.f);
          float corner = 0.f;
          if(dy==0&&dx==0)corner=cHW;
          if(dy==0&&dx==2)corner=cH0;
          if(dy==2&&dx==0)corner=c0W;
          if(dy==2&&dx==2)corner=c00;
          s += wp[dy*3+dx]*(T-rm-cm+corner);
        }
      }
    }
    avg[tid] = s*(1.f/16384.f);
  }
  __syncthreads();
  if(tid<24){
    float s = fc1b[tid];
    const float* w = fc1w + (size_t)tid*384;
    for(int c=0;c<384;c++) s += w[c]*avg[c];
    y1[tid] = fmaxf(s,0.f);
  }
  __syncthreads();
  {
    float s = fc2b[tid];
    const float* w = fc2w + (size_t)tid*24;
    #pragma unroll
    for(int j=0;j<24;j++) s += w[j]*y1[j];
    Lb[tid] = s/(1.f+__expf(-s));
  }
  __syncthreads();
  if(tid<48){
    const float* w = po1 + (size_t)tid*384;
    float s = 0.f;
    for(int c=0;c<384;c++) s += w[c]*Lb[c];
    constv[b*48+tid] = s;
  }
}

// per (b,h): normalize, softmax; m2o written FRAGMENT-MAJOR:
// addr = (((b*12+ck)*3+mt)*64 + quad*16+mrow)*8 + j  for (o=mt*16+mrow, hd=ck*32+quad*8+j)
__global__ __launch_bounds__(256) void k_attn(const float* __restrict__ sred,
                                              const float* __restrict__ qn2,
                                              const float* __restrict__ temp,
                                              const float* __restrict__ po1,
                                              ushort_t* __restrict__ m2o){
  int h = blockIdx.x, b = blockIdx.y, tid = threadIdx.x;
  __shared__ float att[2304];
  __shared__ float nq[48], nk[48];
  const float* kn2 = qn2 + 1536;
  if(tid<48)      nq[tid]    = fmaxf(sqrtf(qn2[(size_t)b*D1 + h*48 + tid]),    1e-12f);
  else if(tid<96) nk[tid-48] = fmaxf(sqrtf(kn2[(size_t)b*D1 + h*48 + tid-48]), 1e-12f);
  __syncthreads();
  float tmp = temp[h];
  const float* Sp = sred + (size_t)(b*HEADS+h)*2304;
  for(int idx=tid; idx<2304; idx+=256){
    int c = idx/48, d = idx - c*48;
    att[idx] = Sp[idx]*tmp/(nq[c]*nk[d]);
  }
  __syncthreads();
  if(tid<48){
    float* row = &att[tid*48];
    float m = -1e30f;
    for(int d=0;d<48;d++) m = fmaxf(m,row[d]);
    float s = 0.f;
    for(int d=0;d<48;d++){ float e=__expf(row[d]-m); row[d]=e; s+=e; }
    float inv = 1.f/s;
    for(int d=0;d<48;d++) row[d]*=inv;
  }
  __syncthreads();
  for(int idx=tid; idx<2304; idx+=256){
    int d = idx/48, o = idx - d*48;
    float s = 0.f;
    for(int c=0;c<48;c++) s += po1[(size_t)o*D1 + h*48 + c]*att[c*48+d];
    int hd = h*48 + d;
    int ck = hd>>5, rem = hd&31, quad = rem>>3, j = rem&7;
    int mt = o>>4, mrow = o&15;
    m2o[((((size_t)b*12 + ck)*3 + mt)*64 + quad*16 + mrow)*8 + j] = f2bf(s);
  }
}

// out = x + constv + M2 @ V via MFMA; 64 pos/block (1024 blocks = 4/CU),
// double-buffered LDS; Af loads coalesced via fragment-major m2o.
#define FROW2 40
__global__ __launch_bounds__(256,4) void k_final(const ushort_t* __restrict__ qkvd,
                                                 const ushort_t* __restrict__ m2o,
                                                 const float* __restrict__ constv,
                                                 const float* __restrict__ x,
                                                 float* __restrict__ out){
  __shared__ __align__(16) ushort_t vT[2][64*FROW2];   // 10240 B
  int tid = threadIdx.x;
  int wave = tid>>6, lane = tid&63;
  int quad = lane>>4, mrow = lane&15;
  int pos0 = blockIdx.x*64;
  int b = blockIdx.y;
  const ushort_t* vb = qkvd + ((size_t)b*1152 + 768)*HW + pos0;
  const ushort_t* AbF = m2o + (size_t)b*18432 + lane*8;
  f32x4 acc[3];
  #pragma unroll
  for(int mt=0;mt<3;mt++) acc[mt] = (f32x4){0.f,0.f,0.f,0.f};

  auto stage = [&](int ck, int buf){
    int ch = tid>>3, pg = tid&7, p0 = pg*8;   // 256 units = 32 ch x 8 pos-groups
    int chg = ch>>3, cl = ch&7;
    short8 v = *(const short8*)(vb + (size_t)(ck*32+ch)*HW + p0);
    ushort_t tmp[8]; *(short8*)tmp = v;
    #pragma unroll
    for(int i=0;i<8;i++){
      int p = p0+i;
      int sl = (chg ^ (p&3) ^ ((p>>3)&3)) & 3;
      vT[buf][p*FROW2 + (sl<<3) + cl] = tmp[i];
    }
  };
  stage(0,0);
  __syncthreads();
  for(int ck=0; ck<12; ck++){
    if(ck<11) stage(ck+1, (ck+1)&1);
    short8 Af[3], Bf;
    #pragma unroll
    for(int mt=0;mt<3;mt++)
      Af[mt] = *(const short8*)(AbF + (size_t)(ck*3 + mt)*512);
    {
      int p = wave*16 + mrow;
      int sl = (quad ^ (p&3) ^ ((p>>3)&3)) & 3;
      Bf = *(const short8*)(&vT[ck&1][p*FROW2 + (sl<<3)]);
    }
    #pragma unroll
    for(int mt=0;mt<3;mt++)
      acc[mt] = __builtin_amdgcn_mfma_f32_16x16x32_bf16(Af[mt], Bf, acc[mt], 0,0,0);
    __syncthreads();
  }
  const float* xb = x + (size_t)b*CC*HW + pos0;
  float* ob = out + (size_t)b*CC*HW + pos0;
  #pragma unroll
  for(int mt=0;mt<3;mt++){
    int p = wave*16 + mrow;
    #pragma unroll
    for(int r=0;r<4;r++){
      int o = mt*16 + quad*4 + r;
      ob[(size_t)o*HW + p] = xb[(size_t)o*HW + p] + constv[b*48+o] + acc[mt][r];
    }
  }
}

extern "C" void kernel_launch(void* const* d_in, const int* in_sizes, int n_in,
                              void* d_out, int out_size, void* d_ws, size_t ws_size,
                              hipStream_t stream){
  const float* x    = (const float*)d_in[0];
  const float* qw   = (const float*)d_in[1];
  const float* dw   = (const float*)d_in[2];
  const float* po1  = (const float*)d_in[3];
  const float* fc1w = (const float*)d_in[4];
  const float* fc1b = (const float*)d_in[5];
  const float* fc2w = (const float*)d_in[6];
  const float* fc2b = (const float*)d_in[7];
  const float* temp = (const float*)d_in[8];
  float* out = (float*)d_out;
  char* ws = (char*)d_ws;

  // workspace layout (~162 MB). xb16 ALIASES Spart (used in disjoint phases).
  ushort_t* qkvd   = (ushort_t*)(ws);                 // 150,994,944
  float*    Spart  = (float*)(ws + 150994944);        // 9,437,184
  ushort_t* xb16   = (ushort_t*)(ws + 150994944);     // 6,489,600 (alias of Spart)
  float*    qn2    = (float*)(ws + 160432128);        // 12,288 (qn2 + kn2)
  float*    xst    = (float*)(ws + 160444416);        // 6,912
  float*    constv = (float*)(ws + 160451328);        // 768
  ushort_t* m2o    = (ushort_t*)(ws + 160452096);     // 147,456 (frag-major [b][12][3][64][8])
  ushort_t* wfp    = (ushort_t*)(ws + 160599552);     // 1,032,192 (frag-major)
  float*    sred   = (float*)(ws + 161631744);        // 294,912

  k_wf    <<<dim3(1152),         256, 0, stream>>>(dw, qw, wfp, qn2);
  k_xpose <<<dim3(130,BB),       256, 0, stream>>>(x, xb16, xst);
  k_conv  <<<dim3(128,9,BB),     256, 0, stream>>>(xb16, wfp, qkvd);
  k_S     <<<dim3(32,HEADS,BB),  256, 0, stream>>>(qkvd, Spart, qn2);
  k_sred  <<<dim3(288),          256, 0, stream>>>(Spart, sred);
  k_mlp   <<<dim3(BB),           384, 0, stream>>>(xst, qw, dw, fc1w, fc1b, fc2w, fc2b, po1, constv);
  k_attn  <<<dim3(HEADS,BB),     256, 0, stream>>>(sred, qn2, temp, po1, m2o);
  k_final <<<dim3(256,BB),       256, 0, stream>>>(qkvd, m2o, constv, x, out);
}